// Round 1
// baseline (277.820 us; speedup 1.0000x reference)
//
#include <hip/hip_runtime.h>
#include <math.h>

#define CC 256      // channels
#define HW 65536    // 256*256 pixels
#define SS 256      // pooled spatial (16*16)

// ws layout (float offsets)
#define WS_X    0        // X[c][s]      256*256
#define WS_XN   65536    // Xn[c][s]     256*256
#define WS_YG   131072   // pooled sup_y [256]
#define WS_INVN 131328   // 1/max(||Xn[:,n]||,1e-4)  [256]
#define WS_SELF 131584   // sel flag as float        [256]

// ---------------------------------------------------------------- pooling
// blocks 0..255: channel c of sup_x -> X[c][0..255]
// block 256:     sup_y -> yg[0..255]
__global__ void pool_kernel(const float* __restrict__ sup_x,
                            const float* __restrict__ sup_y,
                            float* __restrict__ ws) {
    int blk = blockIdx.x;
    int t   = threadIdx.x;                 // column w = t
    const float* src = (blk < CC) ? (sup_x + (size_t)blk * HW) : sup_y;
    float* dst       = (blk < CC) ? (ws + WS_X + blk * SS) : (ws + WS_YG);

    for (int py = 0; py < 16; ++py) {
        float acc = 0.f;
        int hbase = py * 16;
        #pragma unroll
        for (int i = 0; i < 16; ++i)
            acc += src[(hbase + i) * 256 + t];   // coalesced rows
        // sum over the 16 columns of one pooled cell (16-lane groups)
        acc += __shfl_down(acc, 8, 16);
        acc += __shfl_down(acc, 4, 16);
        acc += __shfl_down(acc, 2, 16);
        acc += __shfl_down(acc, 1, 16);
        if ((t & 15) == 0)
            dst[py * 16 + (t >> 4)] = acc * (1.f / 256.f);
    }
}

// ---------------------------------------------------- gram + softmax + Xn
// block i: w1 row i -> softmax -> tridiag T row -> Xn[i][:]
__global__ void calib_kernel(const float* __restrict__ cal,
                             float* __restrict__ ws) {
    int i = blockIdx.x;
    int j = threadIdx.x;
    const float* X = ws + WS_X;
    float* Xn = ws + WS_XN;

    __shared__ float xi[SS];
    __shared__ float e[CC];
    __shared__ float red[256];
    __shared__ float T[3];

    xi[j] = X[i * SS + j];
    __syncthreads();

    // w1[i][j] = X[i,:] . X[j,:]
    float dot = 0.f;
    const float* Xj = X + j * SS;
    for (int s = 0; s < SS; ++s) dot += xi[s] * Xj[s];

    // row max
    red[j] = dot; __syncthreads();
    for (int off = 128; off > 0; off >>= 1) {
        if (j < off) red[j] = fmaxf(red[j], red[j + off]);
        __syncthreads();
    }
    float m = red[0];
    __syncthreads();

    float ev = expf(dot - m);
    e[j] = ev;
    red[j] = ev; __syncthreads();
    for (int off = 128; off > 0; off >>= 1) {
        if (j < off) red[j] += red[j + off];
        __syncthreads();
    }
    float esum = red[0];
    __syncthreads();

    if (j < 3) {
        int jj = i + j - 1;
        float tv = 0.f;
        if (jj >= 0 && jj < CC) {
            float soft = e[jj] / esum;
            tv = (1.f + 0.2f * soft) * cal[i * CC + jj];
        }
        T[j] = tv;
    }
    __syncthreads();

    float v = T[1] * xi[j];
    if (i > 0)      v += T[0] * X[(i - 1) * SS + j];
    if (i < CC - 1) v += T[2] * X[(i + 1) * SS + j];
    Xn[i * SS + j] = v;   // coalesced
}

// ------------------------------------------------ proto inv-norms + sel
__global__ void prep_kernel(float* __restrict__ ws) {
    int n = threadIdx.x;
    const float* Xn = ws + WS_XN;
    float s = 0.f;
    for (int c = 0; c < CC; ++c) {     // coalesced per c-row
        float v = Xn[c * SS + n];
        s += v * v;
    }
    ws[WS_INVN + n] = 1.f / fmaxf(sqrtf(s), 1e-4f);
    float g = ws[WS_YG + n];
    ws[WS_SELF + n] = (g > 0.5f) ? 1.f : 0.f;
}

// ------------------------------------- fused GEMM + softmax + argmax
// block: 64 pixels x 256 protos, K=256 in chunks of 16.
// thread (tm = tid&7, tn = tid>>3): 8 pixels (tm*8+i) x 8 protos (tn*8+j).
#define MB 64
#define KC 16
#define DT_S 260            // dt row stride (pad to dodge phase-2 conflicts)
#define SMEM_FLOATS (64 * DT_S + 256 + 256 + 256 + 64)

__global__ __launch_bounds__(256, 2)
void main_kernel(const float* __restrict__ qry,
                 const float* __restrict__ ws,
                 float* __restrict__ out) {
    extern __shared__ float smem[];
    float* qs = smem;                  // [KC][64]
    float* bs = smem + KC * 64;        // [KC][256]
    float* dt = smem;                  // [64][DT_S] (reuses qs/bs region)
    float* invn_s = smem + 64 * DT_S;  // [256]
    float* self_s = invn_s + 256;      // [256]
    float* qsqa   = self_s + 256;      // [256]
    float* invq   = qsqa + 256;        // [64]

    int tid = threadIdx.x;
    int tm = tid & 7, tn = tid >> 3;
    int p0 = blockIdx.x * MB;
    const float* Xn = ws + WS_XN;

    invn_s[tid] = ws[WS_INVN + tid];
    self_s[tid] = ws[WS_SELF + tid];

    float acc[8][8];
    #pragma unroll
    for (int i = 0; i < 8; ++i)
        #pragma unroll
        for (int jj = 0; jj < 8; ++jj) acc[i][jj] = 0.f;

    float qpart = 0.f;   // partial sum-of-squares for pixel (tid & 63)

    for (int k0 = 0; k0 < CC; k0 += KC) {
        __syncthreads();
        // stage qry chunk [KC][64]  (coalesced; thread covers pixel tid&63)
        #pragma unroll
        for (int u = 0; u < 4; ++u) {
            int e2 = tid + 256 * u;
            int kk = e2 >> 6, p = e2 & 63;
            float v = qry[(size_t)(k0 + kk) * HW + p0 + p];
            qs[kk * 64 + p] = v;
            qpart += v * v;
        }
        // stage Xn chunk [KC][256] (coalesced)
        #pragma unroll
        for (int u = 0; u < KC; ++u)
            bs[u * 256 + tid] = Xn[(k0 + u) * SS + tid];
        __syncthreads();

        #pragma unroll
        for (int kk = 0; kk < KC; ++kk) {
            float4 qa = *reinterpret_cast<const float4*>(&qs[kk * 64 + tm * 8]);
            float4 qb = *reinterpret_cast<const float4*>(&qs[kk * 64 + tm * 8 + 4]);
            float4 ba = *reinterpret_cast<const float4*>(&bs[kk * 256 + tn * 8]);
            float4 bb = *reinterpret_cast<const float4*>(&bs[kk * 256 + tn * 8 + 4]);
            float q8[8] = {qa.x, qa.y, qa.z, qa.w, qb.x, qb.y, qb.z, qb.w};
            float b8[8] = {ba.x, ba.y, ba.z, ba.w, bb.x, bb.y, bb.z, bb.w};
            #pragma unroll
            for (int i = 0; i < 8; ++i)
                #pragma unroll
                for (int jj = 0; jj < 8; ++jj)
                    acc[i][jj] += q8[i] * b8[jj];
        }
    }

    // reduce per-pixel ||q||^2: threads {p, p+64, p+128, p+192} hold partials
    qsqa[tid] = qpart;
    __syncthreads();
    if (tid < MB) {
        float s = qsqa[tid] + qsqa[tid + 64] + qsqa[tid + 128] + qsqa[tid + 192];
        invq[tid] = 1.f / fmaxf(sqrtf(s), 1e-4f);
    }
    __syncthreads();   // also protects qs/bs before dt overwrite

    // write masked+scaled dists tile to LDS
    #pragma unroll
    for (int i = 0; i < 8; ++i) {
        float iq = invq[tm * 8 + i] * 20.f;
        #pragma unroll
        for (int jj = 0; jj < 8; jj += 4) {
            int n = tn * 8 + jj;
            float4 dv;
            float d0 = acc[i][jj + 0] * invn_s[n + 0] * iq;
            float d1 = acc[i][jj + 1] * invn_s[n + 1] * iq;
            float d2 = acc[i][jj + 2] * invn_s[n + 2] * iq;
            float d3 = acc[i][jj + 3] * invn_s[n + 3] * iq;
            dv.x = (self_s[n + 0] > 0.5f) ? d0 : -1e9f;
            dv.y = (self_s[n + 1] > 0.5f) ? d1 : -1e9f;
            dv.z = (self_s[n + 2] > 0.5f) ? d2 : -1e9f;
            dv.w = (self_s[n + 3] > 0.5f) ? d3 : -1e9f;
            *reinterpret_cast<float4*>(&dt[(tm * 8 + i) * DT_S + n]) = dv;
        }
    }
    __syncthreads();

    // phase 2: 4 threads per pixel scan n = k4 + 4t (conflict-free with DT_S=260)
    int p = tid >> 2, k4 = tid & 3;
    float vmax = -3.4e38f; int varg = 0;
    for (int t = 0; t < 64; ++t) {
        int n = k4 + 4 * t;
        float v = dt[p * DT_S + n];
        if (v > vmax) { vmax = v; varg = n; }   // strict > keeps lowest n
    }
    #pragma unroll
    for (int off = 1; off < 4; off <<= 1) {
        float ov = __shfl_xor(vmax, off, 4);
        int   oa = __shfl_xor(varg, off, 4);
        if (ov > vmax || (ov == vmax && oa < varg)) { vmax = ov; varg = oa; }
    }
    float s1 = 0.f, s2 = 0.f;
    for (int t = 0; t < 64; ++t) {
        int n = k4 + 4 * t;
        float v = dt[p * DT_S + n];
        float ev = expf(v - vmax);      // masked: expf(-1e9) == 0 -> contributes 0
        s1 += ev;
        s2 += ev * v;
    }
    s1 += __shfl_xor(s1, 1, 4); s1 += __shfl_xor(s1, 2, 4);
    s2 += __shfl_xor(s2, 1, 4); s2 += __shfl_xor(s2, 2, 4);
    if (k4 == 0) {
        out[p0 + p]      = s2 / s1;     // pred_grid
        out[HW + p0 + p] = (float)varg; // debug_assign
    }
}

// ----------------------------------------------------------------- launch
extern "C" void kernel_launch(void* const* d_in, const int* in_sizes, int n_in,
                              void* d_out, int out_size, void* d_ws, size_t ws_size,
                              hipStream_t stream) {
    const float* qry   = (const float*)d_in[0];
    const float* sup_x = (const float*)d_in[1];
    const float* sup_y = (const float*)d_in[2];
    // d_in[3] = s_init_seed (unused by reference)
    const float* cal   = (const float*)d_in[4];
    float* out = (float*)d_out;
    float* ws  = (float*)d_ws;

    pool_kernel<<<257, 256, 0, stream>>>(sup_x, sup_y, ws);
    calib_kernel<<<256, 256, 0, stream>>>(cal, ws);
    prep_kernel<<<1, 256, 0, stream>>>(ws);
    main_kernel<<<1024, 256, SMEM_FLOATS * sizeof(float), stream>>>(qry, ws, out);
}